// Round 3
// baseline (192.061 us; speedup 1.0000x reference)
//
#include <hip/hip_runtime.h>

#define KLEN 2048
#define SCH 16          // trellis steps per thread
#define TPR 128         // threads per row
#define NEGV (-1e4f)

struct SM {
  float y1[KLEN];             // systematic, natural order
  float y1i[KLEN];            // systematic, interleaved (precomputed once)
  float Lint[KLEN];           // La for decoder 1 (natural order)
  float A[KLEN];              // La for decoder 2 (interleaved order); bits staging
  unsigned short perm[KLEN];
  unsigned short invp[KLEN];
  float fTot[16];
  float bTot[16];
  unsigned int eTot[2];
};

template <int CTRL>
__device__ __forceinline__ float dppf(float old_, float src) {
  return __int_as_float(__builtin_amdgcn_update_dpp(
      __float_as_int(old_), __float_as_int(src), CTRL, 0xF, 0xF, false));
}

template <int CTRL>
__device__ __forceinline__ void shift16(const float (&X)[16], float (&T)[16]) {
#pragma unroll
  for (int e = 0; e < 16; ++e) T[e] = dppf<CTRL>(X[e], X[e]);
}

__device__ __forceinline__ void cp16(float (&D)[16], const float (&S)[16]) {
#pragma unroll
  for (int e = 0; e < 16; ++e) D[e] = S[e];
}

// Z = X (later) (x) Y (earlier), max-plus, NO normalization
__device__ __forceinline__ void comb(const float (&X)[16], const float (&Y)[16],
                                     float (&Z)[16]) {
#pragma unroll
  for (int i = 0; i < 4; ++i)
#pragma unroll
    for (int j = 0; j < 4; ++j)
      Z[i * 4 + j] = fmaxf(fmaxf(X[i * 4 + 0] + Y[0 * 4 + j], X[i * 4 + 1] + Y[1 * 4 + j]),
                           fmaxf(X[i * 4 + 2] + Y[2 * 4 + j], X[i * 4 + 3] + Y[3 * 4 + j]));
}

// chunk matrix over SCH steps: M[to][from], normalized to max 0
__device__ __forceinline__ void buildM(const float (&p)[SCH], const float (&q)[SCH],
                                       float (&M)[16]) {
  float ppq = p[0] + q[0], pmq = p[0] - q[0];
  M[0] = -ppq; M[1] =  ppq; M[2] = NEGV; M[3] = NEGV;
  M[4] = NEGV; M[5] = NEGV; M[6] =  pmq; M[7] = -pmq;
  M[8] =  ppq; M[9] = -ppq; M[10] = NEGV; M[11] = NEGV;
  M[12] = NEGV; M[13] = NEGV; M[14] = -pmq; M[15] =  pmq;
#pragma unroll
  for (int k = 1; k < SCH; ++k) {
    ppq = p[k] + q[k]; pmq = p[k] - q[k];
#pragma unroll
    for (int j = 0; j < 4; ++j) {
      float r0 = M[0 * 4 + j], r1 = M[1 * 4 + j], r2 = M[2 * 4 + j], r3 = M[3 * 4 + j];
      M[0 * 4 + j] = fmaxf(r0 - ppq, r1 + ppq);
      M[2 * 4 + j] = fmaxf(r0 + ppq, r1 - ppq);
      M[1 * 4 + j] = fmaxf(r2 + pmq, r3 - pmq);
      M[3 * 4 + j] = fmaxf(r2 - pmq, r3 + pmq);
    }
  }
  float mx = M[0];
#pragma unroll
  for (int e = 1; e < 16; ++e) mx = fmaxf(mx, M[e]);
#pragma unroll
  for (int e = 0; e < 16; ++e) M[e] -= mx;
}

// one BCJR pass; contiguous reads; scattered write via widx
__device__ __forceinline__ void bcjr_pass(
    const float* ys, const float* La, float* dst, const unsigned short* widx,
    int finalLLR, const float (&q)[SCH], float (&fTot)[16], float (&bTot)[16],
    int c, int lane, int wr) {
  const int base = c * SCH;
  float p[SCH];
  {
    const float4* y4 = (const float4*)(ys + base);
    const float4* l4 = (const float4*)(La + base);
#pragma unroll
    for (int k = 0; k < SCH / 4; ++k) {
      float4 yv = y4[k], lv = l4[k];
      p[4 * k + 0] = yv.x + 0.5f * lv.x;
      p[4 * k + 1] = yv.y + 0.5f * lv.y;
      p[4 * k + 2] = yv.z + 0.5f * lv.z;
      p[4 * k + 3] = yv.w + 0.5f * lv.w;
    }
  }

  float P[16];
  buildM(p, q, P);
  float Q[16];
  cp16(Q, P);

  const int rl = lane & 15;
  const int row = lane >> 4;

  // ---- forward inclusive scan, all-DPP ----
  {
    float T[16], N[16];
    shift16<0x111>(P, T); if (rl >= 1) { comb(P, T, N); cp16(P, N); }
    shift16<0x112>(P, T); if (rl >= 2) { comb(P, T, N); cp16(P, N); }
    shift16<0x114>(P, T); if (rl >= 4) { comb(P, T, N); cp16(P, N); }
    shift16<0x118>(P, T); if (rl >= 8) { comb(P, T, N); cp16(P, N); }
    shift16<0x142>(P, T); if (row & 1)  { comb(P, T, N); cp16(P, N); }  // bcast15
    shift16<0x143>(P, T); if (row >= 2) { comb(P, T, N); cp16(P, N); }  // bcast31
  }
  // ---- backward inclusive (suffix) scan: DPP in-row + 2 bpermute stitch levels ----
  {
    float T[16], N[16];
    shift16<0x101>(Q, T); if (rl <= 14) { comb(T, Q, N); cp16(Q, N); }
    shift16<0x102>(Q, T); if (rl <= 13) { comb(T, Q, N); cp16(Q, N); }
    shift16<0x104>(Q, T); if (rl <= 11) { comb(T, Q, N); cp16(Q, N); }
    shift16<0x108>(Q, T); if (rl <= 7)  { comb(T, Q, N); cp16(Q, N); }
#pragma unroll
    for (int d = 1; d <= 2; d <<= 1) {
      int src = (row + d) << 4;   // next-row lane0 carries that row-group's total
      float T2[16];
#pragma unroll
      for (int e = 0; e < 16; ++e) T2[e] = __shfl(Q[e], src);
      if (row + d <= 3) { float N2[16]; comb(T2, Q, N2); cp16(Q, N2); }
    }
  }

  // ---- cross-wave exchange ----
  if (wr == 0 && lane == 63) {
#pragma unroll
    for (int e = 0; e < 16; ++e) fTot[e] = P[e];
  }
  if (wr == 1 && lane == 0) {
#pragma unroll
    for (int e = 0; e < 16; ++e) bTot[e] = Q[e];
  }
  __syncthreads();
  if (wr == 1) {
    float T[16], N[16];
#pragma unroll
    for (int e = 0; e < 16; ++e) T[e] = fTot[e];
    comb(P, T, N); cp16(P, N);
  } else {
    float T[16], N[16];
#pragma unroll
    for (int e = 0; e < 16; ++e) T[e] = bTot[e];
    comb(T, Q, N); cp16(Q, N);
  }

  // alpha at chunk start = col 0 of prefix at c-1 (delta start => exact col 0)
  float a[4];
  {
    float a0 = __shfl(P[0], lane - 1), a1 = __shfl(P[4], lane - 1);
    float a2 = __shfl(P[8], lane - 1), a3 = __shfl(P[12], lane - 1);
    if (c == 0) { a[0] = 0.f; a[1] = NEGV; a[2] = NEGV; a[3] = NEGV; }
    else {
      if (lane == 0) { a0 = fTot[0]; a1 = fTot[4]; a2 = fTot[8]; a3 = fTot[12]; }
      a[0] = 0.f; a[1] = a1 - a0; a[2] = a2 - a0; a[3] = a3 - a0;
    }
  }

  // beta at chunk end = col-max of suffix at c+1
  float b[4];
  {
    float m0 = fmaxf(fmaxf(Q[0], Q[4]), fmaxf(Q[8],  Q[12]));
    float m1 = fmaxf(fmaxf(Q[1], Q[5]), fmaxf(Q[9],  Q[13]));
    float m2 = fmaxf(fmaxf(Q[2], Q[6]), fmaxf(Q[10], Q[14]));
    float m3 = fmaxf(fmaxf(Q[3], Q[7]), fmaxf(Q[11], Q[15]));
    float b0 = __shfl(m0, lane + 1), b1 = __shfl(m1, lane + 1);
    float b2 = __shfl(m2, lane + 1), b3 = __shfl(m3, lane + 1);
    if (c == TPR - 1) { b[0] = b[1] = b[2] = b[3] = 0.f; }
    else {
      if (lane == 63) {
        b0 = fmaxf(fmaxf(bTot[0], bTot[4]), fmaxf(bTot[8],  bTot[12]));
        b1 = fmaxf(fmaxf(bTot[1], bTot[5]), fmaxf(bTot[9],  bTot[13]));
        b2 = fmaxf(fmaxf(bTot[2], bTot[6]), fmaxf(bTot[10], bTot[14]));
        b3 = fmaxf(fmaxf(bTot[3], bTot[7]), fmaxf(bTot[11], bTot[15]));
      }
      b[0] = 0.f; b[1] = b1 - b0; b[2] = b2 - b0; b[3] = b3 - b0;
    }
  }

  // local beta walk
  float bet[SCH][4];
  bet[SCH - 1][0] = b[0]; bet[SCH - 1][1] = b[1];
  bet[SCH - 1][2] = b[2]; bet[SCH - 1][3] = b[3];
#pragma unroll
  for (int k = SCH - 1; k >= 1; --k) {
    float ppq = p[k] + q[k], pmq = p[k] - q[k];
    float B0 = bet[k][0], B1 = bet[k][1], B2 = bet[k][2], B3 = bet[k][3];
    bet[k - 1][0] = fmaxf(B0 - ppq, B2 + ppq);
    bet[k - 1][1] = fmaxf(B2 - ppq, B0 + ppq);
    bet[k - 1][2] = fmaxf(B3 - pmq, B1 + pmq);
    bet[k - 1][3] = fmaxf(B1 - pmq, B3 + pmq);
  }

  // alpha walk + LLR + scattered write
#pragma unroll
  for (int k = 0; k < SCH; ++k) {
    float ppq = p[k] + q[k], pmq = p[k] - q[k];
    float B0 = bet[k][0], B1 = bet[k][1], B2 = bet[k][2], B3 = bet[k][3];
    float m1 = fmaxf(fmaxf(a[0] + ppq + B2, a[1] + ppq + B0),
                     fmaxf(a[2] + pmq + B1, a[3] + pmq + B3));
    float m0 = fmaxf(fmaxf(a[0] - ppq + B0, a[1] - ppq + B2),
                     fmaxf(a[2] - pmq + B3, a[3] - pmq + B1));
    float llr = m1 - m0;
    float val = finalLLR ? llr : (llr - 2.f * p[k]);
    dst[widx[base + k]] = val;
    float a0 = a[0], a1 = a[1], a2 = a[2], a3 = a[3];
    a[0] = fmaxf(a0 - ppq, a1 + ppq);
    a[2] = fmaxf(a0 + ppq, a1 - ppq);
    a[1] = fmaxf(a2 + pmq, a3 - pmq);
    a[3] = fmaxf(a2 - pmq, a3 + pmq);
  }
}

__device__ __forceinline__ unsigned fsm_compose(unsigned f, unsigned g) {
  unsigned nm = 0;
#pragma unroll
  for (int s = 0; s < 4; ++s) {
    unsigned gs = (g >> (8 * s)) & 3u;
    nm |= ((f >> (8 * gs)) & 0xFFu) << (8 * s);
  }
  return nm;
}

__global__ __launch_bounds__(TPR, 1) void turbo_kernel(
    const int* __restrict__ xg, const float* __restrict__ n1g,
    const float* __restrict__ n2g, const float* __restrict__ n3g,
    const int* __restrict__ pg, float* __restrict__ outg) {
  __shared__ SM sm;
  const int tid = threadIdx.x;
  const int c = tid, lane = tid & 63, wr = tid >> 6;
  const size_t rb = (size_t)blockIdx.x * KLEN;

  // ---- load: perm, bits->A(int), y1, Lint=0; parity noise -> registers ----
  int* Ai = (int*)sm.A;
  for (int i = tid; i < KLEN; i += TPR) {
    sm.perm[i] = (unsigned short)pg[i];
    int xv = xg[rb + i];
    Ai[i] = xv;
    sm.y1[i] = (2.f * xv - 1.f) + n1g[rb + i];
    sm.Lint[i] = 0.f;
  }
  float q2[SCH], q3[SCH];
  {
    size_t g0 = rb + (size_t)c * SCH;
#pragma unroll
    for (int k = 0; k < SCH; ++k) { q2[k] = n2g[g0 + k]; q3[k] = n3g[g0 + k]; }
  }
  __syncthreads();

  // ---- one-time: invp, interleaved systematic ----
  for (int i = tid; i < KLEN; i += TPR) {
    sm.invp[sm.perm[i]] = (unsigned short)i;
    sm.y1i[i] = sm.y1[sm.perm[i]];
  }

  // ---- RSC encode (both parities) via FSM shuffle scan ----
  unsigned ub1 = 0, ub2 = 0;
#pragma unroll
  for (int k = 0; k < SCH; ++k) {
    int t = c * SCH + k;
    ub1 |= (unsigned)(Ai[t] & 1) << k;
    ub2 |= (unsigned)(Ai[sm.perm[t]] & 1) << k;
  }
  unsigned m1 = 0x03020100u, m2 = 0x03020100u;
#pragma unroll
  for (int k = 0; k < SCH; ++k) {
    unsigned st1 = ((ub1 >> k) & 1) ? 0x03010002u : 0x01030200u;
    unsigned st2 = ((ub2 >> k) & 1) ? 0x03010002u : 0x01030200u;
    m1 = fsm_compose(st1, m1);
    m2 = fsm_compose(st2, m2);
  }
#pragma unroll
  for (int i = 0; i < 6; ++i) {
    const int d = 1 << i;
    unsigned t1 = __shfl_up(m1, d), t2 = __shfl_up(m2, d);
    if (lane >= d) { m1 = fsm_compose(m1, t1); m2 = fsm_compose(m2, t2); }
  }
  if (wr == 0 && lane == 63) { sm.eTot[0] = m1; sm.eTot[1] = m2; }
  __syncthreads();
  {
    unsigned w1 = sm.eTot[0], w2 = sm.eTot[1];
    unsigned f1 = wr ? fsm_compose(m1, w1) : m1;
    unsigned f2 = wr ? fsm_compose(m2, w2) : m2;
    unsigned pf1 = __shfl_up(f1, 1), pf2 = __shfl_up(f2, 1);
    int s1 = (c == 0) ? 0 : (lane == 0 ? (int)(w1 & 3u) : (int)(pf1 & 3u));
    int s2 = (c == 0) ? 0 : (lane == 0 ? (int)(w2 & 3u) : (int)(pf2 & 3u));
#pragma unroll
    for (int k = 0; k < SCH; ++k) {
      { int u = (ub1 >> k) & 1, a = u ^ (s1 >> 1) ^ (s1 & 1), par = a ^ (s1 & 1);
        q2[k] += 2.f * par - 1.f; s1 = (a << 1) | (s1 >> 1); }
      { int u = (ub2 >> k) & 1, a = u ^ (s2 >> 1) ^ (s2 & 1), par = a ^ (s2 & 1);
        q3[k] += 2.f * par - 1.f; s2 = (a << 1) | (s2 >> 1); }
    }
  }
  __syncthreads();  // bits consumed; A becomes interleaved-La buffer

  // ---- 6 turbo iterations ----
#pragma unroll 1
  for (int it = 0; it < 6; ++it) {
    // dec1: natural reads; scatter Le1 into interleaved order (A[invp[n]])
    bcjr_pass(sm.y1, sm.Lint, sm.A, sm.invp, 0, q2, sm.fTot, sm.bTot, c, lane, wr);
    __syncthreads();
    // dec2: fully contiguous reads; scatter (deinterleave) into Lint
    const int fin = (it == 5);
    bcjr_pass(sm.y1i, sm.A, sm.Lint, sm.perm, fin, q3, sm.fTot, sm.bTot, c, lane, wr);
    __syncthreads();
  }

  // ---- Lint holds deinterleaved L2; coalesced store ----
  for (int i = tid; i < KLEN; i += TPR) outg[rb + i] = sm.Lint[i];
}

extern "C" void kernel_launch(void* const* d_in, const int* in_sizes, int n_in,
                              void* d_out, int out_size, void* d_ws, size_t ws_size,
                              hipStream_t stream) {
  (void)n_in; (void)d_ws; (void)ws_size; (void)out_size;
  const int* x    = (const int*)d_in[0];
  const float* n1 = (const float*)d_in[1];
  const float* n2 = (const float*)d_in[2];
  const float* n3 = (const float*)d_in[3];
  const int* perm = (const int*)d_in[4];
  float* out = (float*)d_out;
  const int K = in_sizes[4];       // 2048
  const int B = in_sizes[0] / K;   // 512 rows, one per block
  turbo_kernel<<<B, TPR, 0, stream>>>(x, n1, n2, n3, perm, out);
}

// Round 4
// 174.655 us; speedup vs baseline: 1.0997x; 1.0997x over previous
//
#include <hip/hip_runtime.h>

#define KLEN 2048
#define SCH 8           // trellis steps per thread
#define TPR 256         // threads per row (4 waves)
#define NEGV (-1e4f)

struct SM {
  float y1[KLEN];             // systematic, natural order
  float y1i[KLEN];            // systematic, interleaved
  float Lint[KLEN];           // La for decoder 1 (natural)
  float A[KLEN];              // La for decoder 2 (interleaved); bits staging
  unsigned short perm[KLEN];
  unsigned short invp[KLEN];
  float fT[4][16];            // per-wave forward totals
  float bT[4][16];            // per-wave backward totals
  unsigned int eT[4][2];      // encoder wave totals
};

template <int CTRL>
__device__ __forceinline__ float dppf(float src) {
  return __int_as_float(__builtin_amdgcn_update_dpp(
      __float_as_int(src), __float_as_int(src), CTRL, 0xF, 0xF, false));
}

template <int CTRL>
__device__ __forceinline__ void shift16(const float (&X)[16], float (&T)[16]) {
#pragma unroll
  for (int e = 0; e < 16; ++e) T[e] = dppf<CTRL>(X[e]);
}

__device__ __forceinline__ void cp16(float (&D)[16], const float (&S)[16]) {
#pragma unroll
  for (int e = 0; e < 16; ++e) D[e] = S[e];
}

__device__ __forceinline__ void ld16(float (&D)[16], const float* S) {
#pragma unroll
  for (int e = 0; e < 16; ++e) D[e] = S[e];
}

// Z = X (later) (x) Y (earlier), max-plus
__device__ __forceinline__ void comb(const float (&X)[16], const float (&Y)[16],
                                     float (&Z)[16]) {
#pragma unroll
  for (int i = 0; i < 4; ++i)
#pragma unroll
    for (int j = 0; j < 4; ++j)
      Z[i * 4 + j] = fmaxf(fmaxf(X[i * 4 + 0] + Y[0 * 4 + j], X[i * 4 + 1] + Y[1 * 4 + j]),
                           fmaxf(X[i * 4 + 2] + Y[2 * 4 + j], X[i * 4 + 3] + Y[3 * 4 + j]));
}

// chunk matrix over SCH steps: M[to][from], normalized to max 0
__device__ __forceinline__ void buildM(const float (&p)[SCH], const float (&q)[SCH],
                                       float (&M)[16]) {
  float ppq = p[0] + q[0], pmq = p[0] - q[0];
  M[0] = -ppq; M[1] =  ppq; M[2] = NEGV; M[3] = NEGV;
  M[4] = NEGV; M[5] = NEGV; M[6] =  pmq; M[7] = -pmq;
  M[8] =  ppq; M[9] = -ppq; M[10] = NEGV; M[11] = NEGV;
  M[12] = NEGV; M[13] = NEGV; M[14] = -pmq; M[15] =  pmq;
#pragma unroll
  for (int k = 1; k < SCH; ++k) {
    ppq = p[k] + q[k]; pmq = p[k] - q[k];
#pragma unroll
    for (int j = 0; j < 4; ++j) {
      float r0 = M[0 * 4 + j], r1 = M[1 * 4 + j], r2 = M[2 * 4 + j], r3 = M[3 * 4 + j];
      M[0 * 4 + j] = fmaxf(r0 - ppq, r1 + ppq);
      M[2 * 4 + j] = fmaxf(r0 + ppq, r1 - ppq);
      M[1 * 4 + j] = fmaxf(r2 + pmq, r3 - pmq);
      M[3 * 4 + j] = fmaxf(r2 - pmq, r3 + pmq);
    }
  }
  float mx = M[0];
#pragma unroll
  for (int e = 1; e < 16; ++e) mx = fmaxf(mx, M[e]);
#pragma unroll
  for (int e = 0; e < 16; ++e) M[e] -= mx;
}

// one BCJR pass: 256 threads (4 waves) x SCH steps, hierarchical scan
__device__ __forceinline__ void bcjr_pass(
    const float* ys, const float* La, float* dst, const unsigned short* widx,
    int finalLLR, const float (&q)[SCH], float (&fT)[4][16], float (&bT)[4][16],
    int c, int lane, int w) {
  const int base = c * SCH;
  float p[SCH];
  {
    const float4* y4 = (const float4*)(ys + base);
    const float4* l4 = (const float4*)(La + base);
#pragma unroll
    for (int k = 0; k < SCH / 4; ++k) {
      float4 yv = y4[k], lv = l4[k];
      p[4 * k + 0] = yv.x + 0.5f * lv.x;
      p[4 * k + 1] = yv.y + 0.5f * lv.y;
      p[4 * k + 2] = yv.z + 0.5f * lv.z;
      p[4 * k + 3] = yv.w + 0.5f * lv.w;
    }
  }

  float P[16];
  buildM(p, q, P);
  float Q[16];
  cp16(Q, P);

  const int rl = lane & 15;
  const int row = lane >> 4;

  // ---- intra-wave forward inclusive scan (DPP) ----
  {
    float T[16], N[16];
    shift16<0x111>(P, T); if (rl >= 1) { comb(P, T, N); cp16(P, N); }
    shift16<0x112>(P, T); if (rl >= 2) { comb(P, T, N); cp16(P, N); }
    shift16<0x114>(P, T); if (rl >= 4) { comb(P, T, N); cp16(P, N); }
    shift16<0x118>(P, T); if (rl >= 8) { comb(P, T, N); cp16(P, N); }
    shift16<0x142>(P, T); if (row & 1)  { comb(P, T, N); cp16(P, N); }  // bcast15
    shift16<0x143>(P, T); if (row >= 2) { comb(P, T, N); cp16(P, N); }  // bcast31
  }
  // ---- intra-wave backward (suffix) scan: DPP in-row + 2 shfl stitch levels ----
  {
    float T[16], N[16];
    shift16<0x101>(Q, T); if (rl <= 14) { comb(T, Q, N); cp16(Q, N); }
    shift16<0x102>(Q, T); if (rl <= 13) { comb(T, Q, N); cp16(Q, N); }
    shift16<0x104>(Q, T); if (rl <= 11) { comb(T, Q, N); cp16(Q, N); }
    shift16<0x108>(Q, T); if (rl <= 7)  { comb(T, Q, N); cp16(Q, N); }
#pragma unroll
    for (int d = 1; d <= 2; d <<= 1) {
      int src = (row + d) << 4;
      float T2[16];
#pragma unroll
      for (int e = 0; e < 16; ++e) T2[e] = __shfl(Q[e], src);
      if (row + d <= 3) { float N2[16]; comb(T2, Q, N2); cp16(Q, N2); }
    }
  }

  // ---- wave totals -> LDS ----
  if (lane == 63) {
#pragma unroll
    for (int e = 0; e < 16; ++e) fT[w][e] = P[e];
  }
  if (lane == 0) {
#pragma unroll
    for (int e = 0; e < 16; ++e) bT[w][e] = Q[e];
  }
  __syncthreads();

  // ---- cross-wave apply ----
  float F[16];                 // product of forward totals of waves < w
  {
    float t[16], n[16];
    if (w >= 1) ld16(F, fT[0]);
    if (w >= 2) { ld16(t, fT[1]); comb(t, F, n); cp16(F, n); }
    if (w >= 3) { ld16(t, fT[2]); comb(t, F, n); cp16(F, n); }
    if (w >= 1) { comb(P, F, n); cp16(P, n); }
  }
  float Bm[16];                // product of backward totals of waves > w
  {
    float t[16], n[16];
    if (w <= 2) ld16(Bm, bT[3]);
    if (w <= 1) { ld16(t, bT[2]); comb(Bm, t, n); cp16(Bm, n); }
    if (w <= 0) { ld16(t, bT[1]); comb(Bm, t, n); cp16(Bm, n); }
    if (w <= 2) { comb(Bm, Q, n); cp16(Q, n); }
  }

  // alpha at chunk start = col 0 of global prefix at c-1
  float a[4];
  {
    float a0 = __shfl(P[0], lane - 1), a1 = __shfl(P[4], lane - 1);
    float a2 = __shfl(P[8], lane - 1), a3 = __shfl(P[12], lane - 1);
    if (c == 0) { a[0] = 0.f; a[1] = NEGV; a[2] = NEGV; a[3] = NEGV; }
    else {
      if (lane == 0) { a0 = F[0]; a1 = F[4]; a2 = F[8]; a3 = F[12]; }
      a[0] = 0.f; a[1] = a1 - a0; a[2] = a2 - a0; a[3] = a3 - a0;
    }
  }

  // beta at chunk end = col-max of global suffix at c+1
  float b[4];
  {
    float m0 = fmaxf(fmaxf(Q[0], Q[4]), fmaxf(Q[8],  Q[12]));
    float m1 = fmaxf(fmaxf(Q[1], Q[5]), fmaxf(Q[9],  Q[13]));
    float m2 = fmaxf(fmaxf(Q[2], Q[6]), fmaxf(Q[10], Q[14]));
    float m3 = fmaxf(fmaxf(Q[3], Q[7]), fmaxf(Q[11], Q[15]));
    float b0 = __shfl(m0, lane + 1), b1 = __shfl(m1, lane + 1);
    float b2 = __shfl(m2, lane + 1), b3 = __shfl(m3, lane + 1);
    if (c == TPR - 1) { b[0] = b[1] = b[2] = b[3] = 0.f; }
    else {
      if (lane == 63) {
        b0 = fmaxf(fmaxf(Bm[0], Bm[4]), fmaxf(Bm[8],  Bm[12]));
        b1 = fmaxf(fmaxf(Bm[1], Bm[5]), fmaxf(Bm[9],  Bm[13]));
        b2 = fmaxf(fmaxf(Bm[2], Bm[6]), fmaxf(Bm[10], Bm[14]));
        b3 = fmaxf(fmaxf(Bm[3], Bm[7]), fmaxf(Bm[11], Bm[15]));
      }
      b[0] = 0.f; b[1] = b1 - b0; b[2] = b2 - b0; b[3] = b3 - b0;
    }
  }

  // local beta walk
  float bet[SCH][4];
  bet[SCH - 1][0] = b[0]; bet[SCH - 1][1] = b[1];
  bet[SCH - 1][2] = b[2]; bet[SCH - 1][3] = b[3];
#pragma unroll
  for (int k = SCH - 1; k >= 1; --k) {
    float ppq = p[k] + q[k], pmq = p[k] - q[k];
    float B0 = bet[k][0], B1 = bet[k][1], B2 = bet[k][2], B3 = bet[k][3];
    bet[k - 1][0] = fmaxf(B0 - ppq, B2 + ppq);
    bet[k - 1][1] = fmaxf(B2 - ppq, B0 + ppq);
    bet[k - 1][2] = fmaxf(B3 - pmq, B1 + pmq);
    bet[k - 1][3] = fmaxf(B1 - pmq, B3 + pmq);
  }

  // alpha walk + LLR + scattered write
#pragma unroll
  for (int k = 0; k < SCH; ++k) {
    float ppq = p[k] + q[k], pmq = p[k] - q[k];
    float B0 = bet[k][0], B1 = bet[k][1], B2 = bet[k][2], B3 = bet[k][3];
    float m1 = fmaxf(fmaxf(a[0] + ppq + B2, a[1] + ppq + B0),
                     fmaxf(a[2] + pmq + B1, a[3] + pmq + B3));
    float m0 = fmaxf(fmaxf(a[0] - ppq + B0, a[1] - ppq + B2),
                     fmaxf(a[2] - pmq + B3, a[3] - pmq + B1));
    float llr = m1 - m0;
    float val = finalLLR ? llr : (llr - 2.f * p[k]);
    dst[widx[base + k]] = val;
    float a0 = a[0], a1 = a[1], a2 = a[2], a3 = a[3];
    a[0] = fmaxf(a0 - ppq, a1 + ppq);
    a[2] = fmaxf(a0 + ppq, a1 - ppq);
    a[1] = fmaxf(a2 + pmq, a3 - pmq);
    a[3] = fmaxf(a2 - pmq, a3 + pmq);
  }
}

__device__ __forceinline__ unsigned fsm_compose(unsigned f, unsigned g) {
  unsigned nm = 0;
#pragma unroll
  for (int s = 0; s < 4; ++s) {
    unsigned gs = (g >> (8 * s)) & 3u;
    nm |= ((f >> (8 * gs)) & 0xFFu) << (8 * s);
  }
  return nm;
}

__global__ __launch_bounds__(TPR, 2) void turbo_kernel(
    const int* __restrict__ xg, const float* __restrict__ n1g,
    const float* __restrict__ n2g, const float* __restrict__ n3g,
    const int* __restrict__ pg, float* __restrict__ outg) {
  __shared__ SM sm;
  const int tid = threadIdx.x;
  const int c = tid, lane = tid & 63, w = tid >> 6;
  const size_t rb = (size_t)blockIdx.x * KLEN;

  // ---- load inputs ----
  int* Ai = (int*)sm.A;
  for (int i = tid; i < KLEN; i += TPR) {
    sm.perm[i] = (unsigned short)pg[i];
    int xv = xg[rb + i];
    Ai[i] = xv;
    sm.y1[i] = (2.f * xv - 1.f) + n1g[rb + i];
    sm.Lint[i] = 0.f;
  }
  float q2[SCH], q3[SCH];
  {
    size_t g0 = rb + (size_t)c * SCH;
#pragma unroll
    for (int k = 0; k < SCH; ++k) { q2[k] = n2g[g0 + k]; q3[k] = n3g[g0 + k]; }
  }
  __syncthreads();

  // ---- one-time: invp, interleaved systematic ----
  for (int i = tid; i < KLEN; i += TPR) {
    sm.invp[sm.perm[i]] = (unsigned short)i;
    sm.y1i[i] = sm.y1[sm.perm[i]];
  }

  // ---- RSC encode via FSM hierarchical scan ----
  unsigned ub1 = 0, ub2 = 0;
#pragma unroll
  for (int k = 0; k < SCH; ++k) {
    int t = c * SCH + k;
    ub1 |= (unsigned)(Ai[t] & 1) << k;
    ub2 |= (unsigned)(Ai[sm.perm[t]] & 1) << k;
  }
  unsigned m1 = 0x03020100u, m2 = 0x03020100u;
#pragma unroll
  for (int k = 0; k < SCH; ++k) {
    unsigned st1 = ((ub1 >> k) & 1) ? 0x03010002u : 0x01030200u;
    unsigned st2 = ((ub2 >> k) & 1) ? 0x03010002u : 0x01030200u;
    m1 = fsm_compose(st1, m1);
    m2 = fsm_compose(st2, m2);
  }
#pragma unroll
  for (int i = 0; i < 6; ++i) {
    const int d = 1 << i;
    unsigned t1 = __shfl_up(m1, d), t2 = __shfl_up(m2, d);
    if (lane >= d) { m1 = fsm_compose(m1, t1); m2 = fsm_compose(m2, t2); }
  }
  if (lane == 63) { sm.eT[w][0] = m1; sm.eT[w][1] = m2; }
  __syncthreads();
  {
    unsigned W1 = 0x03020100u, W2 = 0x03020100u;
    if (w >= 1) { W1 = sm.eT[0][0]; W2 = sm.eT[0][1]; }
    if (w >= 2) { W1 = fsm_compose(sm.eT[1][0], W1); W2 = fsm_compose(sm.eT[1][1], W2); }
    if (w >= 3) { W1 = fsm_compose(sm.eT[2][0], W1); W2 = fsm_compose(sm.eT[2][1], W2); }
    unsigned f1 = fsm_compose(m1, W1), f2 = fsm_compose(m2, W2);
    unsigned pf1 = __shfl_up(f1, 1), pf2 = __shfl_up(f2, 1);
    int s1 = (c == 0) ? 0 : (lane == 0 ? (int)(W1 & 3u) : (int)(pf1 & 3u));
    int s2 = (c == 0) ? 0 : (lane == 0 ? (int)(W2 & 3u) : (int)(pf2 & 3u));
#pragma unroll
    for (int k = 0; k < SCH; ++k) {
      { int u = (ub1 >> k) & 1, a = u ^ (s1 >> 1) ^ (s1 & 1), par = a ^ (s1 & 1);
        q2[k] += 2.f * par - 1.f; s1 = (a << 1) | (s1 >> 1); }
      { int u = (ub2 >> k) & 1, a = u ^ (s2 >> 1) ^ (s2 & 1), par = a ^ (s2 & 1);
        q3[k] += 2.f * par - 1.f; s2 = (a << 1) | (s2 >> 1); }
    }
  }
  __syncthreads();  // bits consumed; A becomes interleaved-La buffer

  // ---- 6 turbo iterations ----
#pragma unroll 1
  for (int it = 0; it < 6; ++it) {
    // dec1: natural reads; scatter Le1 into interleaved order
    bcjr_pass(sm.y1, sm.Lint, sm.A, sm.invp, 0, q2, sm.fT, sm.bT, c, lane, w);
    __syncthreads();
    // dec2: contiguous reads; scatter (deinterleave) into Lint
    const int fin = (it == 5);
    bcjr_pass(sm.y1i, sm.A, sm.Lint, sm.perm, fin, q3, sm.fT, sm.bT, c, lane, w);
    __syncthreads();
  }

  // ---- Lint holds deinterleaved L2; coalesced store ----
  for (int i = tid; i < KLEN; i += TPR) outg[rb + i] = sm.Lint[i];
}

extern "C" void kernel_launch(void* const* d_in, const int* in_sizes, int n_in,
                              void* d_out, int out_size, void* d_ws, size_t ws_size,
                              hipStream_t stream) {
  (void)n_in; (void)d_ws; (void)ws_size; (void)out_size;
  const int* x    = (const int*)d_in[0];
  const float* n1 = (const float*)d_in[1];
  const float* n2 = (const float*)d_in[2];
  const float* n3 = (const float*)d_in[3];
  const int* perm = (const int*)d_in[4];
  float* out = (float*)d_out;
  const int K = in_sizes[4];       // 2048
  const int B = in_sizes[0] / K;   // 512 rows, one per block
  turbo_kernel<<<B, TPR, 0, stream>>>(x, n1, n2, n3, perm, out);
}